// Round 13
// baseline (421.757 us; speedup 1.0000x reference)
//
#include <hip/hip_runtime.h>
#include <hip/hip_bf16.h>
#include <hip/hip_cooperative_groups.h>

// out[b,e] = m[c,e] + sum_d z[b,d] * L[c,e,d],  c = components[b]
// v13: SINGLE cooperative launch. Evidence: gmm is pinned at 87-103us across
// seven schedule/tile variants (v5-v12) -> that axis is exhausted. Anchors
// (v5/v10/v12) give E2E = gmm + 182 +- 2; of the 182, ~76us is inter-dispatch
// gap (~15-16us x 5 nodes; cross-checked on v3's 6-node chain). Fusing our 3
// kernels into one cooperative kernel (2x grid.sync) removes 2 nodes (~30us)
// and absorbs build+zgather work. Phases: (A) block 0 builds rowmap/counts
// (proven atomic logic); sync; (B) 800 zgather units over 640 blocks (proven
// v6 unit body); sync; (C) proven v6 gmm pipeline verbatim (the 87.5us
// config). Runtime fallback to the proven 3-launch chain if cooperative
// capacity/support is insufficient.

namespace cg = cooperative_groups;

#define DDIM  2048
#define BSAMP 1024
#define KCOMP 10
#define MPAD  160                      // max n_k pad; Binom(1024,0.1)+6sigma
#define NT    32                       // block N tile
#define BK    32                       // d-elems per iteration
#define NITER (DDIM / BK)              // 64
#define TILEB 10240                    // zb tile stride (640 chunks, packed)
#define ABYTES TILEB
#define BBYTES 4096                    // fp32 B stage
#define STAGE_BYTES (ABYTES + BBYTES)  // 14336; x2 = 28672 -> 5 blocks/CU
#define NWG   (KCOMP * 64)             // 640 GEMM blocks
#define ZUNITS (KCOMP * 80)            // 800 zgather units

typedef __attribute__((ext_vector_type(8))) short bf16x8;  // 8 bf16 = 4 VGPRs
typedef __attribute__((ext_vector_type(4))) float f32x4;

__device__ __forceinline__ void async16(void* lds, const void* g) {
    __builtin_amdgcn_global_load_lds(
        (const __attribute__((address_space(1))) void*)g,
        (__attribute__((address_space(3))) void*)lds, 16, 0, 0);
}

__device__ __forceinline__ short bfs(float x) {
    __hip_bfloat16 h = __float2bfloat16(x);   // RNE
    return *reinterpret_cast<short*>(&h);
}

// ---- zgather unit (proven v6 body; unit u = k*80 + sp) ----
__device__ __forceinline__ void zgather_unit(const float* __restrict__ z,
                                             const int* __restrict__ rowmap,
                                             short* __restrict__ zb,
                                             int u, int t) {
    const int k  = u / 80;
    const int sp = u - k * 80;                  // slot pair / macro-row
    const int c  = t & 7;                       // chunk within macro-row
    const int g  = c & 3;
    const int s0 = rowmap[k * MPAD + 2 * sp]     & (BSAMP - 1);
    const int s1 = rowmap[k * MPAD + 2 * sp + 1] & (BSAMP - 1);
    const int src = (c >> 2) ? s1 : s0;
    const int swz = (c ^ (sp & 7)) * 16;        // byte offset within 128B
    char* kbase = (char*)zb + (size_t)k * NITER * TILEB + sp * 128 + swz;
#pragma unroll
    for (int p = 0; p < 2; ++p) {
        const int it = p * 32 + (t >> 3);
        const float* zr = z + (size_t)src * DDIM + it * BK + g * 8;
        f32x4 x = *(const f32x4*)zr;
        f32x4 y = *(const f32x4*)(zr + 4);
        bf16x8 r;
#pragma unroll
        for (int i = 0; i < 4; ++i) { r[i] = bfs(x[i]); r[4 + i] = bfs(y[i]); }
        *(bf16x8*)(kbase + (size_t)it * TILEB) = r;
    }
}

// ---- GEMM body (proven v6 pipeline verbatim; params k, n0) ----
__device__ __forceinline__ void gmm_body(char* smem,
                                         const short* __restrict__ zb,
                                         const float* __restrict__ mvec,
                                         const float* __restrict__ Lmat,
                                         const int* __restrict__ rowmap,
                                         const int* __restrict__ counts,
                                         float* __restrict__ out,
                                         int k, int n0, int t) {
    const int lane = t & 63;
    const int w    = t >> 6;
    const int mh   = w >> 1;          // wave M-half (80 rows)
    const int nh   = w & 1;           // wave N-half (16 cols)
    const float* Lk = Lmat + (size_t)k * DDIM * DDIM;
    const char* zt  = (const char*)zb + (size_t)k * NITER * TILEB;
    const int cnt  = counts[k];

    int mtmax = (cnt - mh * 80 + 15) >> 4;
    mtmax = mtmax < 0 ? 0 : (mtmax > 5 ? 5 : mtmax);

    const int br = t >> 3,          bc = ((t & 7) ^ (br & 7)) * 4;
    const unsigned ub = (unsigned)(t & ~63) * 16;   // wave-uniform byte base

    auto stage = [&](int buf, int it) {
        char* lb = smem + buf * STAGE_BYTES;
        const char* at = zt + (size_t)it * TILEB;
        async16(lb + ub,        at + t * 16);
        async16(lb + 4096 + ub, at + 4096 + t * 16);
        if (t < 128)
            async16(lb + 8192 + ub, at + 8192 + t * 16);
        async16(lb + ABYTES + ub,
                Lk + (size_t)(n0 + br) * DDIM + it * BK + bc);
    };

    f32x4 acc[5];
#pragma unroll
    for (int mt = 0; mt < 5; ++mt) acc[mt] = (f32x4){0.f, 0.f, 0.f, 0.f};

    stage(0, 0);
    __syncthreads();                 // drains vmcnt -> buf0 ready

    const int fr = lane & 15;        // frag row
    const int g  = lane >> 4;        // k-group (8 elems) of this lane
    const int rb = nh * 16 + fr;     // B row (block-relative e)
    const int h0 = ((2 * g)     ^ (rb & 7)) * 4;
    const int h1 = ((2 * g + 1) ^ (rb & 7)) * 4;
    const int frh = fr >> 1;
    const int fra = (fr & 1) * 4 + g;
    const int abase = (mh * 40 + frh) * 128 + ((fra ^ frh) * 16);

    for (int it = 0; it < NITER; ++it) {
        if (it + 1 < NITER) stage((it + 1) & 1, it + 1);
        const char* lb = smem + (it & 1) * STAGE_BYTES;
        const float* B = (const float*)(lb + ABYTES);

        f32x4 x = *(const f32x4*)(B + rb * 32 + h0);
        f32x4 y = *(const f32x4*)(B + rb * 32 + h1);
        bf16x8 bb;
#pragma unroll
        for (int i = 0; i < 4; ++i) { bb[i] = bfs(x[i]); bb[4 + i] = bfs(y[i]); }

#pragma unroll
        for (int mt = 0; mt < 5; ++mt) {
            if (mt < mtmax) {        // wave-uniform guard, static acc index
                bf16x8 a = *(const bf16x8*)(lb + abase + mt * 1024);
                acc[mt] = __builtin_amdgcn_mfma_f32_16x16x32_bf16(a, bb, acc[mt], 0, 0, 0);
            }
        }
        __syncthreads();             // cur buf consumed; prefetch drained
    }

    // epilogue: C/D layout col=lane&15, row=(lane>>4)*4+reg (m89-verified)
    const int rquad = g * 4;
    const int e  = n0 + nh * 16 + fr;
    const float mu = mvec[k * DDIM + e];
#pragma unroll
    for (int mt = 0; mt < 5; ++mt) {
        if (mt < mtmax) {
            const int sb = mh * 80 + mt * 16 + rquad;
#pragma unroll
            for (int r = 0; r < 4; ++r) {
                const int slot = sb + r;
                if (slot < cnt) {
                    const int b = rowmap[k * MPAD + slot];
                    out[(size_t)b * DDIM + e] = acc[mt][r] + mu;
                }
            }
        }
    }
}

// ---- fused cooperative kernel ----
__global__ __launch_bounds__(256, 3)
void gmm_fused(const float* __restrict__ z,
               const float* __restrict__ mvec,
               const float* __restrict__ Lmat,
               const int* __restrict__ comp,
               int* __restrict__ rowmap,
               int* __restrict__ counts,
               short* __restrict__ zb,
               float* __restrict__ out) {
    __shared__ __attribute__((aligned(16))) char smem[2 * STAGE_BYTES];
    const int t   = threadIdx.x;
    const int bid = blockIdx.x;

    // phase A: block 0 builds the canonical bucket map (proven atomic logic)
    if (bid == 0) {
        __shared__ int sc[KCOMP];
        if (t < KCOMP) sc[t] = 0;
        __syncthreads();
#pragma unroll
        for (int j = 0; j < 4; ++j) {
            const int i = j * 256 + t;
            const int c = comp[i];
            const int r = atomicAdd(&sc[c], 1);
            if (r < MPAD) rowmap[c * MPAD + r] = i;
        }
        __syncthreads();
        if (t < KCOMP) counts[t] = sc[t];
    }
    cg::this_grid().sync();

    // phase B: 800 zgather units over 640 blocks
    zgather_unit(z, rowmap, zb, bid, t);
    if (bid < ZUNITS - NWG) zgather_unit(z, rowmap, zb, NWG + bid, t);
    cg::this_grid().sync();

    // phase C: GEMM (k = bid/64, ntile = bid%64)
    gmm_body(smem, zb, mvec, Lmat, rowmap, counts, out,
             bid >> 6, (bid & 63) * NT, t);
}

// ---- fallback chain (proven 3-launch path) ----
__global__ void build_map_k(const int* __restrict__ comp,
                            int* __restrict__ rowmap,
                            int* __restrict__ counts) {
    __shared__ int sc[KCOMP];
    const int t = threadIdx.x;
    if (t < KCOMP) sc[t] = 0;
    __syncthreads();
    const int c = comp[t];
    const int r = atomicAdd(&sc[c], 1);
    if (r < MPAD) rowmap[c * MPAD + r] = t;
    __syncthreads();
    if (t < KCOMP) counts[t] = sc[t];
}

__global__ void zgather_k(const float* __restrict__ z,
                          const int* __restrict__ rowmap,
                          short* __restrict__ zb) {
    zgather_unit(z, rowmap, zb, blockIdx.x, threadIdx.x);
}

__global__ __launch_bounds__(256, 2)
void gmm_k(const short* __restrict__ zb,
           const float* __restrict__ mvec,
           const float* __restrict__ Lmat,
           const int* __restrict__ rowmap,
           const int* __restrict__ counts,
           float* __restrict__ out) {
    __shared__ __attribute__((aligned(16))) char smem[2 * STAGE_BYTES];
    gmm_body(smem, zb, mvec, Lmat, rowmap, counts, out,
             (int)blockIdx.x >> 6, ((int)blockIdx.x & 63) * NT,
             (int)threadIdx.x);
}

extern "C" void kernel_launch(void* const* d_in, const int* in_sizes, int n_in,
                              void* d_out, int out_size, void* d_ws, size_t ws_size,
                              hipStream_t stream) {
    const float* z    = (const float*)d_in[0];
    const float* mvec = (const float*)d_in[1];
    const float* Lmat = (const float*)d_in[2];
    const int* comp   = (const int*)d_in[3];
    float* out        = (float*)d_out;

    int* rowmap = (int*)d_ws;                         // K*MPAD ints = 6400 B
    int* counts = rowmap + KCOMP * MPAD;              // K ints
    short* zb   = (short*)((char*)d_ws + 8192);       // 6.55 MB packed image

    static int coop = -1;
    if (coop < 0) {                                   // one-time host queries
        hipDeviceProp_t prop{};
        int dev = 0;
        (void)hipGetDevice(&dev);
        (void)hipGetDeviceProperties(&prop, dev);
        int nb = 0;
        (void)hipOccupancyMaxActiveBlocksPerMultiprocessor(&nb, gmm_fused, 256, 0);
        coop = (prop.cooperativeLaunch &&
                (long)nb * prop.multiProcessorCount >= NWG) ? 1 : 0;
    }
    if (coop) {
        void* args[] = {(void*)&z, (void*)&mvec, (void*)&Lmat, (void*)&comp,
                        (void*)&rowmap, (void*)&counts, (void*)&zb, (void*)&out};
        if (hipLaunchCooperativeKernel(gmm_fused, dim3(NWG), dim3(256),
                                       args, 0, stream) == hipSuccess)
            return;
        coop = 0;                                     // fall through once
    }
    build_map_k<<<1, BSAMP, 0, stream>>>(comp, rowmap, counts);
    zgather_k<<<ZUNITS, 256, 0, stream>>>(z, rowmap, zb);
    gmm_k<<<NWG, 256, 0, stream>>>(zb, mvec, Lmat, rowmap, counts, out);
}

// Round 14
// 280.614 us; speedup vs baseline: 1.5030x; 1.5030x over previous
//
#include <hip/hip_runtime.h>
#include <hip/hip_bf16.h>

// out[b,e] = m[c,e] + sum_d z[b,d] * L[c,e,d],  c = components[b]
// v14: many small independent blocks (the resident-block-rate lever).
// Evidence: per-CU staging rate across all anchors = ~4.7 B/cyc per RESIDENT
// BLOCK (v5/v6/v12 @2.5 res -> 9-12 B/cyc, 87-103us; v11 @1 res -> 10, 87us;
// v3 @4+ res -> 18.9, 65us; m97 ref @3-4 -> 21.8). Schedule depth, counted
// vmcnt, XCD swizzle, byte count, fusion: all falsified (v6-v13). Rate
// scales with independent barrier groups -> maximize resident blocks.
// Block = (k, ntile32, M-HALF 80 rows): 128 threads (2 waves, wave 80x16),
// LDS 20.5 KB dbuf -> 1280 blocks, 5 resident/CU, no merge (M-split outputs
// disjoint). B re-read x2 (336 MB) + A 419 MB = 755 MB @ predicted ~14 TB/s
// -> gmm ~55-70us. zb image/zgather/build_map/frag maps/epilogue proven
// (m-half A source = contiguous 5120B; macro-row&7 invariant under +40).

#define DDIM  2048
#define BSAMP 1024
#define KCOMP 10
#define MPAD  160                      // max n_k pad; Binom(1024,0.1)+6sigma
#define NT    32                       // block N tile
#define BK    32                       // d-elems per iteration
#define NITER (DDIM / BK)              // 64
#define TILEB 10240                    // zb tile stride (640 chunks, packed)
#define AHALF 5120                     // A half-tile bytes per iteration
#define ALDSB 6144                     // A LDS region (incl. 1KB clamp pad)
#define BBYTES 4096                    // fp32 B stage
#define STAGE_BYTES (ALDSB + BBYTES)   // 10240; x2 = 20480 -> 5+ blocks/CU
#define NWG   (KCOMP * 64 * 2)         // 1280 blocks

typedef __attribute__((ext_vector_type(8))) short bf16x8;  // 8 bf16 = 4 VGPRs
typedef __attribute__((ext_vector_type(4))) float f32x4;

__device__ __forceinline__ void async16(void* lds, const void* g) {
    __builtin_amdgcn_global_load_lds(
        (const __attribute__((address_space(1))) void*)g,
        (__attribute__((address_space(3))) void*)lds, 16, 0, 0);
}

__device__ __forceinline__ short bfs(float x) {
    __hip_bfloat16 h = __float2bfloat16(x);   // RNE
    return *reinterpret_cast<short*>(&h);
}

// Kernel 1: counting-bucket the 1024 samples by component (proven v1-v13).
__global__ void build_map(const int* __restrict__ comp,
                          int* __restrict__ rowmap,
                          int* __restrict__ counts) {
    __shared__ int sc[KCOMP];
    const int t = threadIdx.x;
    if (t < KCOMP) sc[t] = 0;
    __syncthreads();
    const int c = comp[t];
    const int r = atomicAdd(&sc[c], 1);
    if (r < MPAD) rowmap[c * MPAD + r] = t;
    __syncthreads();
    if (t < KCOMP) counts[t] = sc[t];
}

// Kernel 2: build the tiled zb image (proven v6-v13, unchanged).
// Block (k, sp) converts slot pair {2sp, 2sp+1}. Thread t, pass p handles
// tile it = p*32 + (t>>3), chunk c = t&7: 8 fp32 of z row (2sp + (c>>2)) at
// d = it*32 + (c&3)*8 -> 16B bf16 at tile + sp*128 + ((c^(sp&7))*16).
__global__ void zgather(const float* __restrict__ z,
                        const int* __restrict__ rowmap,
                        short* __restrict__ zb) {
    const int k  = blockIdx.x;
    const int sp = blockIdx.y;                  // slot pair / macro-row
    const int t  = threadIdx.x;
    const int c  = t & 7;                       // chunk within macro-row
    const int g  = c & 3;
    const int s0 = rowmap[k * MPAD + 2 * sp]     & (BSAMP - 1);
    const int s1 = rowmap[k * MPAD + 2 * sp + 1] & (BSAMP - 1);
    const int src = (c >> 2) ? s1 : s0;
    const int swz = (c ^ (sp & 7)) * 16;        // byte offset within 128B
    char* kbase = (char*)zb + (size_t)k * NITER * TILEB + sp * 128 + swz;
#pragma unroll
    for (int p = 0; p < 2; ++p) {
        const int it = p * 32 + (t >> 3);
        const float* zr = z + (size_t)src * DDIM + it * BK + g * 8;
        f32x4 x = *(const f32x4*)zr;
        f32x4 y = *(const f32x4*)(zr + 4);
        bf16x8 r;
#pragma unroll
        for (int i = 0; i < 4; ++i) { r[i] = bfs(x[i]); r[4 + i] = bfs(y[i]); }
        *(bf16x8*)(kbase + (size_t)it * TILEB) = r;
    }
}

// Kernel 3: grid = 1280, block = 128 (2 waves). bid -> mh = bid&1,
// ntile = (bid>>1)&63, k = bid>>7. Block tile 80x32; wave tile 80x16
// (nh = wave id). acc[5]. v6 sync structure (2-buffer __syncthreads).
// A stage: half-tile = contiguous 5120B at zt + it*TILEB + mh*AHALF;
//   3 uniform ops/thread (op2 clamp-dups chunk 319 into the 1KB pad).
// A frag (block-local): ml = mt*8 + frh; ml&7 = frh; global macro-row
//   mh*40+ml has (gml&7) = frh too (40 = 0 mod 8) -> proven swizzle holds:
//   addr = frh*128 + ((fra^frh)*16) + mt*1024.
// B stage: 256 chunks over 128 threads, 2 uniform ops (proven map).
__global__ __launch_bounds__(128, 4)
void gmm_gemm(const short* __restrict__ zb,
              const float* __restrict__ mvec,
              const float* __restrict__ Lmat,
              const int* __restrict__ rowmap,
              const int* __restrict__ counts,
              float* __restrict__ out) {
    __shared__ __attribute__((aligned(16))) char smem[2 * STAGE_BYTES];
    const int t    = threadIdx.x;     // 0..127
    const int lane = t & 63;
    const int nh   = t >> 6;          // wave id = N-half (16 cols)
    const int bid  = blockIdx.x;
    const int mh   = bid & 1;         // M-half (80 rows)
    const int n0   = ((bid >> 1) & 63) * NT;
    const int k    = bid >> 7;
    const float* Lk = Lmat + (size_t)k * DDIM * DDIM;
    const char* zt  = (const char*)zb + (size_t)k * NITER * TILEB;
    const int cnt  = counts[k];

    // count-aware trim: this block's rows are mh*80 + mt*16 + {0..15}
    int mtmax = (cnt - mh * 80 + 15) >> 4;
    mtmax = mtmax < 0 ? 0 : (mtmax > 5 ? 5 : mtmax);

    // B staging: 256 chunks (row = c>>3, h = c&7), ops c = t and c = 128+t
    const int br0 = t >> 3,        bc0 = ((t & 7) ^ (br0 & 7)) * 4;
    const int c1  = 128 + t;
    const int br1 = c1 >> 3,       bc1 = ((c1 & 7) ^ (br1 & 7)) * 4;
    // A staging: 320 chunks; op2 clamp-dups (src chunk 319, dest pad region)
    const int ac2 = (256 + t < 320) ? (256 + t) : 319;
    const unsigned ub = (unsigned)(t & ~63) * 16;   // wave-uniform byte base

    auto stage = [&](int buf, int it) {             // 5 uniform ops/thread
        char* lb = smem + buf * STAGE_BYTES;
        const char* at = zt + (size_t)it * TILEB + mh * AHALF;
        async16(lb + ub,          at + t * 16);
        async16(lb + 2048 + ub,   at + 2048 + t * 16);
        async16(lb + 4096 + ub,   at + ac2 * 16);
        async16(lb + ALDSB + ub,
                Lk + (size_t)(n0 + br0) * DDIM + it * BK + bc0);
        async16(lb + ALDSB + 2048 + ub,
                Lk + (size_t)(n0 + br1) * DDIM + it * BK + bc1);
    };

    f32x4 acc[5];
#pragma unroll
    for (int mt = 0; mt < 5; ++mt) acc[mt] = (f32x4){0.f, 0.f, 0.f, 0.f};

    stage(0, 0);
    __syncthreads();                 // drains vmcnt -> buf0 ready

    const int fr = lane & 15;        // frag row
    const int g  = lane >> 4;        // k-group (8 elems) of this lane
    const int rb = nh * 16 + fr;     // B row (block-relative e), 0..31
    const int h0 = ((2 * g)     ^ (rb & 7)) * 4;
    const int h1 = ((2 * g + 1) ^ (rb & 7)) * 4;
    const int frh = fr >> 1;
    const int fra = (fr & 1) * 4 + g;
    const int abase = frh * 128 + ((fra ^ frh) * 16);   // block-local

    for (int it = 0; it < NITER; ++it) {
        if (it + 1 < NITER) stage((it + 1) & 1, it + 1);
        const char* lb = smem + (it & 1) * STAGE_BYTES;
        const float* B = (const float*)(lb + ALDSB);

        f32x4 x = *(const f32x4*)(B + rb * 32 + h0);
        f32x4 y = *(const f32x4*)(B + rb * 32 + h1);
        bf16x8 bb;
#pragma unroll
        for (int i = 0; i < 4; ++i) { bb[i] = bfs(x[i]); bb[4 + i] = bfs(y[i]); }

#pragma unroll
        for (int mt = 0; mt < 5; ++mt) {
            if (mt < mtmax) {        // wave-uniform guard, static acc index
                bf16x8 a = *(const bf16x8*)(lb + abase + mt * 1024);
                acc[mt] = __builtin_amdgcn_mfma_f32_16x16x32_bf16(a, bb, acc[mt], 0, 0, 0);
            }
        }
        __syncthreads();             // cur buf consumed; prefetch drained
    }

    // epilogue: C/D layout col=lane&15, row=(lane>>4)*4+reg (m89-verified)
    const int rquad = g * 4;
    const int e  = n0 + nh * 16 + fr;
    const float mu = mvec[k * DDIM + e];
#pragma unroll
    for (int mt = 0; mt < 5; ++mt) {
        if (mt < mtmax) {
            const int sb = mh * 80 + mt * 16 + rquad;
#pragma unroll
            for (int r = 0; r < 4; ++r) {
                const int slot = sb + r;
                if (slot < cnt) {
                    const int b = rowmap[k * MPAD + slot];
                    out[(size_t)b * DDIM + e] = acc[mt][r] + mu;
                }
            }
        }
    }
}

extern "C" void kernel_launch(void* const* d_in, const int* in_sizes, int n_in,
                              void* d_out, int out_size, void* d_ws, size_t ws_size,
                              hipStream_t stream) {
    const float* z    = (const float*)d_in[0];
    const float* mvec = (const float*)d_in[1];
    const float* Lmat = (const float*)d_in[2];
    const int* comp   = (const int*)d_in[3];
    float* out        = (float*)d_out;

    int* rowmap = (int*)d_ws;                         // K*MPAD ints = 6400 B
    int* counts = rowmap + KCOMP * MPAD;              // K ints
    short* zb   = (short*)((char*)d_ws + 8192);       // 6.55 MB packed image

    build_map<<<1, BSAMP, 0, stream>>>(comp, rowmap, counts);
    zgather<<<dim3(KCOMP, MPAD / 2), 256, 0, stream>>>(z, rowmap, zb);
    gmm_gemm<<<NWG, 128, 0, stream>>>(zb, mvec, Lmat, rowmap, counts, out);
}